// Round 6
// baseline (163.057 us; speedup 1.0000x reference)
//
#include <hip/hip_runtime.h>

// ---------------------------------------------------------------------------
// QuaternionLinear == one dense GEMM: out[M,N] = x[M,K] @ W_eff[N,K]^T + bias
//   M = 16384 (B*S), N = 2048 (OUT_F), K = 2048 (IN_F)
// Pipeline: cvt_x (fp32->bf16) ; pack_w (build W_eff bf16) ; qgemm.
// qgemm: 256x256 tile, BK=64, 8 waves (2x4), per-wave 128x64, 16x16x32 MFMA,
// chunk-XOR swizzle (T2), counted vmcnt(4) (T3/T4), setprio (T5), XCD
// swizzle (T1).
// R6: ONE sync point per K-tile. A double-buffered (2x32KB), B TRIPLE-
// buffered (3x32KB) = 160KB LDS. B(t+2) stages land in buf (t+2)%3 which is
// disjoint from the read buf t%3 -> the mid-tile barrier+drain of R5 is
// unnecessary. No per-phase asm waits at all: compiler tracks ds_read->MFMA
// deps with fine-grained lgkmcnt. Single end-of-tile lgkm(0)+vmcnt(4)+barrier.
// ---------------------------------------------------------------------------

typedef unsigned short u16;
typedef __bf16 bf16x8 __attribute__((ext_vector_type(8)));
typedef float f32x4 __attribute__((ext_vector_type(4)));

#define QM 16384
#define QN 2048
#define QK 2048

__device__ __forceinline__ u16 f2bf(float f) {
    union { float f; unsigned u; } v;
    v.f = f;
    unsigned r = v.u + 0x7FFFu + ((v.u >> 16) & 1u);
    return (u16)(r >> 16);
}

__device__ __forceinline__ void async_copy16(const u16* g, u16* l) {
    __builtin_amdgcn_global_load_lds(
        (const __attribute__((address_space(1))) void*)g,
        (__attribute__((address_space(3))) void*)l,
        16, 0, 0);
}

// ---------------------------------------------------------------------------
__global__ void cvt_x_kernel(const float* __restrict__ x, u16* __restrict__ y, int n4) {
    for (int i = blockIdx.x * blockDim.x + threadIdx.x; i < n4; i += gridDim.x * blockDim.x) {
        float4 v = reinterpret_cast<const float4*>(x)[i];
        ushort4 o;
        o.x = f2bf(v.x); o.y = f2bf(v.y); o.z = f2bf(v.z); o.w = f2bf(v.w);
        reinterpret_cast<ushort4*>(y)[i] = o;
    }
}

// ---------------------------------------------------------------------------
__global__ void pack_w_kernel(const float* __restrict__ wr, const float* __restrict__ wi,
                              const float* __restrict__ wj, const float* __restrict__ wk,
                              u16* __restrict__ W) {
    int i = blockIdx.x * blockDim.x + threadIdx.x;
    if (i >= QN * (QK / 4)) return;
    int n = i >> 9;
    int p = i & 511;
    int q = n >> 2, co = n & 3;
    int base = (q << 9) + p;
    float r  = wr[base], ii = wi[base], jj = wj[base], kk = wk[base];
    float e0, e1, e2, e3;
    if      (co == 0) { e0 = r;  e1 = -ii; e2 = -jj; e3 = -kk; }
    else if (co == 1) { e0 = ii; e1 = r;   e2 = -jj; e3 = kk;  }
    else if (co == 2) { e0 = jj; e1 = ii;  e2 = r;   e3 = -kk; }
    else              { e0 = kk; e1 = -ii; e2 = jj;  e3 = r;   }
    ushort4 o;
    o.x = f2bf(e0); o.y = f2bf(e1); o.z = f2bf(e2); o.w = f2bf(e3);
    reinterpret_cast<ushort4*>(W)[(n << 9) + p] = o;
}

// ---------------------------------------------------------------------------
// LDS (u16 elems): A bufs [0,32768) = 2 x 16384; B bufs [32768,81920) = 3 x
// 16384. Buf = 256 rows x 64 cols; physical 16B-chunk (r,cp) holds logical
// (r, cp ^ (r&7)) [involution, both-sides swizzle].
// Per K-tile t: read A-buf t&1 and B-buf t%3; stage A(t+1)->A-buf (t+1)&1,
// B(t+2)->B-buf (t+2)%3. One end-of-tile sync: lgkm(0)+vmcnt(4)+barrier.
// Race-safety:
//   [1] A(t+1) dest buf^1: its tile-(t-1) readers drained at t-1's end
//       (lgkm(0) before barrier); residency for t+1 via end vmcnt(4).
//   [2] B(t+2) dest (t+2)%3 disjoint from read buf t%3 and t+1's buf.
//       B-buf t%3 is next written at tile t+1 (B(t+3)), after my end
//       lgkm(0)+barrier has drained my b-reads.
//   [3] vmcnt(4) at end: queue = [B(t+1)x4, A(t+1)x4, B(t+2)x4]; wait to 4
//       => tile t+1 fully resident; B(t+2) stays in flight.
// ---------------------------------------------------------------------------
__global__ __launch_bounds__(512, 2) void qgemm_kernel(const u16* __restrict__ A,
                                                       const u16* __restrict__ B,
                                                       const float* __restrict__ bias,
                                                       float* __restrict__ C) {
    __shared__ __align__(16) u16 L[81920];      // 160 KB

    const int bid = blockIdx.x;                 // 512 blocks, %8==0
    const int swz = (bid & 7) * 64 + (bid >> 3);
    const int bm = swz >> 3;                    // 0..63
    const int bn = swz & 7;                     // 0..7

    const int tid = threadIdx.x;
    const int wid = tid >> 6, lane = tid & 63;
    const int wm = wid >> 2, wn = wid & 3;
    const int lr = lane & 15, lg = lane >> 4;

    const u16* Asrc = A + (size_t)bm * 256 * QK;
    const u16* Bsrc = B + (size_t)bn * 256 * QK;

    // staging: half-tile = 128 rows x 64 cols; thread covers rows {rA, rA+64}
    const int rA  = tid >> 3;                        // 0..63
    const int clA = ((tid & 7) ^ (rA & 7)) << 3;     // pre-swizzled global col
    const size_t soff = (size_t)rA * QK + clA;

    f32x4 acc[8][4];
#pragma unroll
    for (int i = 0; i < 8; ++i)
#pragma unroll
        for (int j = 0; j < 4; ++j)
            acc[i][j] = (f32x4){0.f, 0.f, 0.f, 0.f};

    auto stage = [&](const u16* src, int lbase, int k0) {
#pragma unroll
        for (int o = 0; o < 2; ++o)
            async_copy16(src + (size_t)(o * 64) * QK + k0 + soff,
                         &L[lbase + o * 4096 + wid * 512]);
    };

    auto rdA = [&](const u16* LA, int mf, int ks) -> bf16x8 {
        const int r = wm * 128 + mf * 16 + lr;
        const int c = ((ks * 4 + lg) ^ (r & 7)) << 3;
        return *(const bf16x8*)&LA[r * 64 + c];
    };
    auto rdB = [&](const u16* LB, int nf, int ks) -> bf16x8 {
        const int r = wn * 64 + nf * 16 + lr;
        const int c = ((ks * 4 + lg) ^ (r & 7)) << 3;
        return *(const bf16x8*)&LB[r * 64 + c];
    };

    auto doTile = [&](const int ab, const int bt, const int bt2, const int t)
        __attribute__((always_inline)) {
        const u16* LA = &L[ab * 16384];
        const u16* LB = &L[32768 + bt * 16384];
        const int tw1 = (t + 1) & 31, tw2 = (t + 2) & 31;
        const int oA = (ab ^ 1) * 16384;          // A dest buf
        const int oB = 32768 + bt2 * 16384;       // B dest buf

        bf16x8 a0[4], a1[4], b0[4], b1[4];

#pragma unroll
        for (int nf = 0; nf < 4; ++nf) b0[nf] = rdB(LB, nf, 0);
#pragma unroll
        for (int mf = 0; mf < 4; ++mf) a0[mf] = rdA(LA, mf, 0);
        stage(Asrc, oA, tw1 * 64);
        __builtin_amdgcn_s_setprio(1);
#pragma unroll
        for (int mf = 0; mf < 4; ++mf)
#pragma unroll
            for (int nf = 0; nf < 4; ++nf)
                acc[mf][nf] = __builtin_amdgcn_mfma_f32_16x16x32_bf16(a0[mf], b0[nf], acc[mf][nf], 0, 0, 0);
        __builtin_amdgcn_s_setprio(0);

#pragma unroll
        for (int mf = 0; mf < 4; ++mf) a1[mf] = rdA(LA, 4 + mf, 0);
#pragma unroll
        for (int nf = 0; nf < 4; ++nf) b1[nf] = rdB(LB, nf, 1);
        stage(Asrc + 128 * QK, oA + 8192, tw1 * 64);
        __builtin_amdgcn_s_setprio(1);
#pragma unroll
        for (int mf = 0; mf < 4; ++mf)
#pragma unroll
            for (int nf = 0; nf < 4; ++nf)
                acc[4 + mf][nf] = __builtin_amdgcn_mfma_f32_16x16x32_bf16(a1[mf], b0[nf], acc[4 + mf][nf], 0, 0, 0);
        __builtin_amdgcn_s_setprio(0);

#pragma unroll
        for (int mf = 0; mf < 4; ++mf) a0[mf] = rdA(LA, mf, 1);
        stage(Bsrc, oB, tw2 * 64);
        __builtin_amdgcn_s_setprio(1);
#pragma unroll
        for (int mf = 0; mf < 4; ++mf)
#pragma unroll
            for (int nf = 0; nf < 4; ++nf)
                acc[mf][nf] = __builtin_amdgcn_mfma_f32_16x16x32_bf16(a0[mf], b1[nf], acc[mf][nf], 0, 0, 0);
        __builtin_amdgcn_s_setprio(0);

#pragma unroll
        for (int mf = 0; mf < 4; ++mf) a1[mf] = rdA(LA, 4 + mf, 1);
        stage(Bsrc + 128 * QK, oB + 8192, tw2 * 64);
        __builtin_amdgcn_s_setprio(1);
#pragma unroll
        for (int mf = 0; mf < 4; ++mf)
#pragma unroll
            for (int nf = 0; nf < 4; ++nf)
                acc[4 + mf][nf] = __builtin_amdgcn_mfma_f32_16x16x32_bf16(a1[mf], b1[nf], acc[4 + mf][nf], 0, 0, 0);
        __builtin_amdgcn_s_setprio(0);

        // single sync point: tile t+1 resident, all my LDS reads drained
        asm volatile("s_waitcnt lgkmcnt(0) vmcnt(4)" ::: "memory");
        __builtin_amdgcn_s_barrier();
    };

    // prologue: A(0)->Abuf0, B(0)->Bbuf0, B(1)->Bbuf1
    stage(Asrc,            0,             0);
    stage(Asrc + 128 * QK, 8192,          0);
    stage(Bsrc,            32768,             0);
    stage(Bsrc + 128 * QK, 32768 + 8192,      0);
    stage(Bsrc,            32768 + 16384,        64);
    stage(Bsrc + 128 * QK, 32768 + 16384 + 8192, 64);
    asm volatile("s_waitcnt vmcnt(4)" ::: "memory");   // A(0),B(0) resident
    __builtin_amdgcn_s_barrier();

    {
        int bt = 0, bt2 = 2;
        for (int t = 0; t < 32; ++t) {
            doTile(t & 1, bt, bt2, t);
            bt  = (bt  == 2) ? 0 : bt  + 1;
            bt2 = (bt2 == 2) ? 0 : bt2 + 1;
        }
    }

    // epilogue: C/D layout col = lane&15, row = (lane>>4)*4 + reg
    const int colbase = bn * 256 + wn * 64;
    const int rowbase = bm * 256 + wm * 128;
    float bsv[4];
#pragma unroll
    for (int nf = 0; nf < 4; ++nf) bsv[nf] = bias[colbase + nf * 16 + lr];
    float* Cb = C + (size_t)rowbase * QN + colbase;
#pragma unroll
    for (int mf = 0; mf < 8; ++mf)
#pragma unroll
        for (int nf = 0; nf < 4; ++nf)
#pragma unroll
            for (int v = 0; v < 4; ++v)
                Cb[(size_t)(mf * 16 + lg * 4 + v) * QN + nf * 16 + lr] = acc[mf][nf][v] + bsv[nf];
}

// ---------------------------------------------------------------------------
extern "C" void kernel_launch(void* const* d_in, const int* in_sizes, int n_in,
                              void* d_out, int out_size, void* d_ws, size_t ws_size,
                              hipStream_t stream) {
    const float* x    = (const float*)d_in[0];
    const float* wr   = (const float*)d_in[1];
    const float* wi   = (const float*)d_in[2];
    const float* wj   = (const float*)d_in[3];
    const float* wk   = (const float*)d_in[4];
    const float* bias = (const float*)d_in[5];
    float* out = (float*)d_out;

    u16* xb = (u16*)d_ws;                                   // 64 MB
    u16* wb = (u16*)((char*)d_ws + (size_t)QM * QK * 2);    // 8 MB

    cvt_x_kernel<<<4096, 256, 0, stream>>>(x, xb, (QM * QK) / 4);
    pack_w_kernel<<<4096, 256, 0, stream>>>(wr, wi, wj, wk, wb);
    qgemm_kernel<<<512, 512, 0, stream>>>(xb, wb, bias, out);
}

// Round 7
// 159.095 us; speedup vs baseline: 1.0249x; 1.0249x over previous
//
#include <hip/hip_runtime.h>

// ---------------------------------------------------------------------------
// QuaternionLinear == one dense GEMM: out[M,N] = x[M,K] @ W_eff[N,K]^T + bias
//   M = 16384 (B*S), N = 2048 (OUT_F), K = 2048 (IN_F)
// Pipeline: prep (fp32->bf16 x + build W_eff, one launch) ; qgemm.
// qgemm: 256x256 tile, BK=64, 8 waves (2x4), per-wave 128x64, 16x16x32 MFMA,
// chunk-XOR swizzle (T2), counted vmcnt(4) (T3/T4), XCD swizzle (T1).
// R7: single sync point per K-tile (A 2-ring, B 3-ring, 160KB LDS) with
//   - compile-time ring indices (6-tile unrolled loop, lcm(2,3)) restoring
//     address CSE (R6 regression: runtime bt -> VALUBusy 18.6->22%),
//   - NO setprio fences: setprio is a side-effecting intrinsic that blocks
//     the scheduler from hoisting next-cluster ds_reads into the current
//     MFMA cluster's shadow (T5 is ~0% on non-lockstep structures, m190);
//     removing the 8 fences/tile lets the compiler software-pipeline
//     reads under MFMA (the m97 mechanism).
// ---------------------------------------------------------------------------

typedef unsigned short u16;
typedef __bf16 bf16x8 __attribute__((ext_vector_type(8)));
typedef float f32x4 __attribute__((ext_vector_type(4)));

#define QM 16384
#define QN 2048
#define QK 2048

__device__ __forceinline__ u16 f2bf(float f) {
    union { float f; unsigned u; } v;
    v.f = f;
    unsigned r = v.u + 0x7FFFu + ((v.u >> 16) & 1u);
    return (u16)(r >> 16);
}

__device__ __forceinline__ void async_copy16(const u16* g, u16* l) {
    __builtin_amdgcn_global_load_lds(
        (const __attribute__((address_space(1))) void*)g,
        (__attribute__((address_space(3))) void*)l,
        16, 0, 0);
}

// ---------------------------------------------------------------------------
// prep: blocks [0,4096) convert x fp32->bf16; blocks [4096,8192) build W_eff.
// ---------------------------------------------------------------------------
__global__ void prep_kernel(const float* __restrict__ x, u16* __restrict__ xb,
                            const float* __restrict__ wr, const float* __restrict__ wi,
                            const float* __restrict__ wj, const float* __restrict__ wk,
                            u16* __restrict__ wb) {
    const int b = blockIdx.x;
    if (b < 4096) {
        const int n4 = (QM * QK) / 4;
        for (int i = b * blockDim.x + threadIdx.x; i < n4; i += 4096 * blockDim.x) {
            float4 v = reinterpret_cast<const float4*>(x)[i];
            ushort4 o;
            o.x = f2bf(v.x); o.y = f2bf(v.y); o.z = f2bf(v.z); o.w = f2bf(v.w);
            reinterpret_cast<ushort4*>(xb)[i] = o;
        }
    } else {
        int i = (b - 4096) * blockDim.x + threadIdx.x;   // [0, QN*QK/4)
        int n = i >> 9;
        int p = i & 511;
        int q = n >> 2, co = n & 3;
        int base = (q << 9) + p;
        float r  = wr[base], ii = wi[base], jj = wj[base], kk = wk[base];
        float e0, e1, e2, e3;
        if      (co == 0) { e0 = r;  e1 = -ii; e2 = -jj; e3 = -kk; }
        else if (co == 1) { e0 = ii; e1 = r;   e2 = -jj; e3 = kk;  }
        else if (co == 2) { e0 = jj; e1 = ii;  e2 = r;   e3 = -kk; }
        else              { e0 = kk; e1 = -ii; e2 = jj;  e3 = r;   }
        ushort4 o;
        o.x = f2bf(e0); o.y = f2bf(e1); o.z = f2bf(e2); o.w = f2bf(e3);
        reinterpret_cast<ushort4*>(wb)[(n << 9) + p] = o;
    }
}

// ---------------------------------------------------------------------------
// LDS (u16 elems): A bufs [0,32768) = 2 x 16384; B bufs [32768,81920) = 3 x
// 16384. Buf = 256 rows x 64 cols; physical 16B-chunk (r,cp) holds logical
// (r, cp ^ (r&7)) [involution, both-sides swizzle].
// Per K-tile t: read A-buf t&1 and B-buf t%3; stage A(t+1)->A-buf (t+1)&1,
// B(t+2)->B-buf (t+2)%3. One end-of-tile sync: lgkm(0)+vmcnt(4)+barrier.
// Race-safety:
//   [1] A(t+1) dest buf^1: its tile-(t-1) readers drained at t-1's end
//       (lgkm(0) before barrier); residency for t+1 via end vmcnt(4).
//   [2] B(t+2) dest (t+2)%3 disjoint from read buf t%3 and t+1's buf.
//       B-buf t%3 next written at tile t+1 (B(t+3)), after my end
//       lgkm(0)+barrier drained my b-reads.
//   [3] vmcnt(4) at end: queue = [B(t+1)x4, A(t+1)x4, B(t+2)x4]; wait to 4
//       => tile t+1 fully resident; B(t+2) stays in flight.
// ---------------------------------------------------------------------------
__global__ __launch_bounds__(512, 2) void qgemm_kernel(const u16* __restrict__ A,
                                                       const u16* __restrict__ B,
                                                       const float* __restrict__ bias,
                                                       float* __restrict__ C) {
    __shared__ __align__(16) u16 L[81920];      // 160 KB

    const int bid = blockIdx.x;                 // 512 blocks, %8==0
    const int swz = (bid & 7) * 64 + (bid >> 3);
    const int bm = swz >> 3;                    // 0..63
    const int bn = swz & 7;                     // 0..7

    const int tid = threadIdx.x;
    const int wid = tid >> 6, lane = tid & 63;
    const int wm = wid >> 2, wn = wid & 3;
    const int lr = lane & 15, lg = lane >> 4;

    const u16* Asrc = A + (size_t)bm * 256 * QK;
    const u16* Bsrc = B + (size_t)bn * 256 * QK;

    // staging: half-tile = 128 rows x 64 cols; thread covers rows {rA, rA+64}
    const int rA  = tid >> 3;                        // 0..63
    const int clA = ((tid & 7) ^ (rA & 7)) << 3;     // pre-swizzled global col
    const size_t soff = (size_t)rA * QK + clA;

    f32x4 acc[8][4];
#pragma unroll
    for (int i = 0; i < 8; ++i)
#pragma unroll
        for (int j = 0; j < 4; ++j)
            acc[i][j] = (f32x4){0.f, 0.f, 0.f, 0.f};

    auto stage = [&](const u16* src, int lbase, int k0) {
#pragma unroll
        for (int o = 0; o < 2; ++o)
            async_copy16(src + (size_t)(o * 64) * QK + k0 + soff,
                         &L[lbase + o * 4096 + wid * 512]);
    };

    auto rdA = [&](const u16* LA, int mf, int ks) -> bf16x8 {
        const int r = wm * 128 + mf * 16 + lr;
        const int c = ((ks * 4 + lg) ^ (r & 7)) << 3;
        return *(const bf16x8*)&LA[r * 64 + c];
    };
    auto rdB = [&](const u16* LB, int nf, int ks) -> bf16x8 {
        const int r = wn * 64 + nf * 16 + lr;
        const int c = ((ks * 4 + lg) ^ (r & 7)) << 3;
        return *(const bf16x8*)&LB[r * 64 + c];
    };

    // ab, bt, bt2 must be LITERAL constants at each call site (address CSE).
    auto doTile = [&](const int ab, const int bt, const int bt2, const int t)
        __attribute__((always_inline)) {
        const u16* LA = &L[ab * 16384];
        const u16* LB = &L[32768 + bt * 16384];
        const int tw1 = (t + 1) & 31, tw2 = (t + 2) & 31;
        const int oA = (ab ^ 1) * 16384;          // A dest buf
        const int oB = 32768 + bt2 * 16384;       // B dest buf

        bf16x8 a0[4], a1[4], b0[4], b1[4];

#pragma unroll
        for (int nf = 0; nf < 4; ++nf) b0[nf] = rdB(LB, nf, 0);
#pragma unroll
        for (int mf = 0; mf < 4; ++mf) a0[mf] = rdA(LA, mf, 0);
        stage(Asrc, oA, tw1 * 64);
#pragma unroll
        for (int mf = 0; mf < 4; ++mf)
#pragma unroll
            for (int nf = 0; nf < 4; ++nf)
                acc[mf][nf] = __builtin_amdgcn_mfma_f32_16x16x32_bf16(a0[mf], b0[nf], acc[mf][nf], 0, 0, 0);

#pragma unroll
        for (int mf = 0; mf < 4; ++mf) a1[mf] = rdA(LA, 4 + mf, 0);
#pragma unroll
        for (int nf = 0; nf < 4; ++nf) b1[nf] = rdB(LB, nf, 1);
        stage(Asrc + 128 * QK, oA + 8192, tw1 * 64);
#pragma unroll
        for (int mf = 0; mf < 4; ++mf)
#pragma unroll
            for (int nf = 0; nf < 4; ++nf)
                acc[4 + mf][nf] = __builtin_amdgcn_mfma_f32_16x16x32_bf16(a1[mf], b0[nf], acc[4 + mf][nf], 0, 0, 0);

#pragma unroll
        for (int mf = 0; mf < 4; ++mf) a0[mf] = rdA(LA, mf, 1);
        stage(Bsrc, oB, tw2 * 64);
#pragma unroll
        for (int mf = 0; mf < 4; ++mf)
#pragma unroll
            for (int nf = 0; nf < 4; ++nf)
                acc[mf][nf] = __builtin_amdgcn_mfma_f32_16x16x32_bf16(a0[mf], b1[nf], acc[mf][nf], 0, 0, 0);

#pragma unroll
        for (int mf = 0; mf < 4; ++mf) a1[mf] = rdA(LA, 4 + mf, 1);
        stage(Bsrc + 128 * QK, oB + 8192, tw2 * 64);
#pragma unroll
        for (int mf = 0; mf < 4; ++mf)
#pragma unroll
            for (int nf = 0; nf < 4; ++nf)
                acc[4 + mf][nf] = __builtin_amdgcn_mfma_f32_16x16x32_bf16(a1[mf], b1[nf], acc[4 + mf][nf], 0, 0, 0);

        // single sync point: tile t+1 resident, all my LDS reads drained
        asm volatile("s_waitcnt lgkmcnt(0) vmcnt(4)" ::: "memory");
        __builtin_amdgcn_s_barrier();
    };

    // prologue: A(0)->Abuf0, B(0)->Bbuf0, B(1)->Bbuf1
    stage(Asrc,            0,             0);
    stage(Asrc + 128 * QK, 8192,          0);
    stage(Bsrc,            32768,             0);
    stage(Bsrc + 128 * QK, 32768 + 8192,      0);
    stage(Bsrc,            32768 + 16384,        64);
    stage(Bsrc + 128 * QK, 32768 + 16384 + 8192, 64);
    asm volatile("s_waitcnt vmcnt(4)" ::: "memory");   // A(0),B(0) resident
    __builtin_amdgcn_s_barrier();

    // 32 tiles = 5 x 6 (lcm of A-ring 2, B-ring 3) + 2 tail; all ring
    // indices literal. Tail stages wrap to tiles 0/1 (dead data, race-safe:
    // target bufs' readers drained at their tiles' end barriers).
    for (int t = 0; t < 30; t += 6) {
        doTile(0, 0, 2, t);
        doTile(1, 1, 0, t + 1);
        doTile(0, 2, 1, t + 2);
        doTile(1, 0, 2, t + 3);
        doTile(0, 1, 0, t + 4);
        doTile(1, 2, 1, t + 5);
    }
    doTile(0, 0, 2, 30);
    doTile(1, 1, 0, 31);

    // epilogue: C/D layout col = lane&15, row = (lane>>4)*4 + reg
    const int colbase = bn * 256 + wn * 64;
    const int rowbase = bm * 256 + wm * 128;
    float bsv[4];
#pragma unroll
    for (int nf = 0; nf < 4; ++nf) bsv[nf] = bias[colbase + nf * 16 + lr];
    float* Cb = C + (size_t)rowbase * QN + colbase;
#pragma unroll
    for (int mf = 0; mf < 8; ++mf)
#pragma unroll
        for (int nf = 0; nf < 4; ++nf)
#pragma unroll
            for (int v = 0; v < 4; ++v)
                Cb[(size_t)(mf * 16 + lg * 4 + v) * QN + nf * 16 + lr] = acc[mf][nf][v] + bsv[nf];
}

// ---------------------------------------------------------------------------
extern "C" void kernel_launch(void* const* d_in, const int* in_sizes, int n_in,
                              void* d_out, int out_size, void* d_ws, size_t ws_size,
                              hipStream_t stream) {
    const float* x    = (const float*)d_in[0];
    const float* wr   = (const float*)d_in[1];
    const float* wi   = (const float*)d_in[2];
    const float* wj   = (const float*)d_in[3];
    const float* wk   = (const float*)d_in[4];
    const float* bias = (const float*)d_in[5];
    float* out = (float*)d_out;

    u16* xb = (u16*)d_ws;                                   // 64 MB
    u16* wb = (u16*)((char*)d_ws + (size_t)QM * QK * 2);    // 8 MB

    prep_kernel<<<8192, 256, 0, stream>>>(x, xb, wr, wi, wj, wk, wb);
    qgemm_kernel<<<512, 512, 0, stream>>>(xb, wb, bias, out);
}